// Round 2
// baseline (670.596 us; speedup 1.0000x reference)
//
#include <hip/hip_runtime.h>

// StackMemory fused kernel for MI355X (gfx950).
// B=4, S=2048, H=1024, NH=16, SLOTS=16, SD=32, HD=64. 8192 tokens total.
// One block (256 threads) per token; thread t = (head = t>>4, slot = t&15).
//
// Outputs concatenated flat: out [8192*1024] | new_stack [8192*8192] | new_mask [8192*256]

constexpr int HDIM  = 1024;
constexpr int COLS  = 273;   // shT column count: 16 heads * 17 cols (+1 spare); stride per d-plane
// shT layout: shT[d * COLS + col], col = nh*17 -> k[nh], col = nh*17 + 1 + slot -> stack[nh][slot]

constexpr long long OUT_STACK_OFF = 8388608LL;     // 4*2048*1024
constexpr long long OUT_MASK_OFF  = 75497472LL;    // + 4*2048*16*16*32

__global__ void transpose_wa(const float* __restrict__ Wa, float* __restrict__ WaT) {
    int o = blockIdx.x * 256 + threadIdx.x;        // 48*1024 elements
    if (o < 48 * 1024) {
        int j = o >> 10, i = o & 1023;
        WaT[o] = Wa[i * 48 + j];
    }
}

__global__ __launch_bounds__(256, 4)
void stack_fused(const float* __restrict__ hid,
                 const float* __restrict__ stack,
                 const float* __restrict__ mask,
                 const float* __restrict__ WaT,   // [48][1024] transposed
                 const float* __restrict__ ba,    // [48]
                 const float* __restrict__ Wd,    // [64][32]
                 const float* __restrict__ bd,    // [32]
                 const float* __restrict__ Wu,    // [32][64]
                 const float* __restrict__ bu,    // [64]
                 const float* __restrict__ Wg,    // [32][1]
                 const float* __restrict__ bg,    // [1]
                 const float* __restrict__ resw,  // [1]
                 float* __restrict__ out)
{
    __shared__ float shT[32 * COLS];      // 34944 B, transposed stack (+k column per head)
    __shared__ float sh_logits[48];       // scaled action logits
    __shared__ float sh_mask[256];
    __shared__ float sh_mem[16 * 33];     // padded mem[nh][d]

    const int t   = threadIdx.x;
    const int tok = blockIdx.x;
    const float4* hid4 = (const float4*)(hid + (size_t)tok * HDIM);
    const float4* stk4 = (const float4*)(stack + (size_t)tok * 8192);

    // zero the spare column (col 272) so no uninitialized LDS is ever read
    if (t < 32) shT[t * COLS + 272] = 0.f;

    // ---- stage stack -> transposed LDS (coalesced float4 global reads) ----
    #pragma unroll
    for (int i = 0; i < 8; ++i) {
        float4 v = stk4[i * 256 + t];
        int e0  = (i * 256 + t) * 4;
        int row = e0 >> 5;                 // 0..255 = nh*16+slot
        int d0  = e0 & 31;
        int col = (row >> 4) * 17 + 1 + (row & 15);
        shT[(d0 + 0) * COLS + col] = v.x;
        shT[(d0 + 1) * COLS + col] = v.y;
        shT[(d0 + 2) * COLS + col] = v.z;
        shT[(d0 + 3) * COLS + col] = v.w;
    }
    sh_mask[t] = mask[(size_t)tok * 256 + t];

    // ---- action logits: wave w computes logits j in [12w, 12w+12) ----
    const int wv = t >> 6, lane = t & 63;
    float4 hreg[4];
    #pragma unroll
    for (int m = 0; m < 4; ++m) hreg[m] = hid4[m * 64 + lane];
    const float4* waT4 = (const float4*)WaT;
    #pragma unroll
    for (int jj = 0; jj < 12; ++jj) {
        int j = wv * 12 + jj;
        float acc = 0.f;
        #pragma unroll
        for (int m = 0; m < 4; ++m) {
            float4 w = waT4[j * 256 + m * 64 + lane];
            acc += hreg[m].x * w.x + hreg[m].y * w.y + hreg[m].z * w.z + hreg[m].w * w.w;
        }
        #pragma unroll
        for (int off = 32; off >= 1; off >>= 1) acc += __shfl_xor(acc, off);
        if (lane == jj) sh_logits[j] = (acc + ba[j]) * 0.125f;  // /sqrt(64)
    }

    // ---- k projection: thread t -> dim d = t&31, heads nh0 = t>>5 and nh0+8 ----
    {
        int d = t & 31;
        int nh0 = t >> 5, nh1 = nh0 + 8;
        float acc0 = bd[d], acc1 = bd[d];
        #pragma unroll
        for (int ii = 0; ii < 16; ++ii) {
            float4 ha = hid4[nh0 * 16 + ii];   // broadcast within lane groups, L1-hot
            float4 hb = hid4[nh1 * 16 + ii];
            float w0 = Wd[(4 * ii + 0) * 32 + d];
            float w1 = Wd[(4 * ii + 1) * 32 + d];
            float w2 = Wd[(4 * ii + 2) * 32 + d];
            float w3 = Wd[(4 * ii + 3) * 32 + d];
            acc0 += ha.x * w0 + ha.y * w1 + ha.z * w2 + ha.w * w3;
            acc1 += hb.x * w0 + hb.y * w1 + hb.z * w2 + hb.w * w3;
        }
        shT[d * COLS + nh0 * 17] = acc0;       // k column
        shT[d * COLS + nh1 * 17] = acc1;
    }
    __syncthreads();

    // ---- per-(head,slot) stack update ----
    const int nh = t >> 4, slot = t & 15;
    float l0 = sh_logits[nh * 3 + 0];
    float l1 = sh_logits[nh * 3 + 1];
    float l2 = sh_logits[nh * 3 + 2];
    float mx = fmaxf(l0, fmaxf(l1, l2));
    float e0 = __expf(l0 - mx), e1 = __expf(l1 - mx), e2 = __expf(l2 - mx);
    float inv = 1.f / (e0 + e1 + e2);
    float a_push = e0 * inv, a_pop = e1 * inv, a_noop = e2 * inv;

    const int colC = nh * 17 + 1 + slot;
    const bool last = (slot == 15);
    float nr[32];
    float gs = 0.f;
    #pragma unroll
    for (int d = 0; d < 32; ++d) {
        float pv = shT[d * COLS + colC - 1];                    // slot0 -> k column
        float cv = shT[d * COLS + colC];
        float nv = last ? 0.f : shT[d * COLS + colC + 1];       // NaN-safe select, not *0
        float v  = a_push * pv + a_pop * nv + a_noop * cv;
        nr[d] = v;
        gs += v * Wg[d];
    }
    gs += bg[0];

    float pm = (slot == 0) ? 1.f : sh_mask[t - 1];
    float cm = sh_mask[t];
    float nm = last ? 0.f : sh_mask[t + 1];
    float nmask = a_push * pm + a_pop * nm + a_noop * cm;

    // write new_stack (float4) + new_mask straight to global
    {
        float4* os4 = (float4*)(out + OUT_STACK_OFF + (size_t)tok * 8192 + t * 32);
        #pragma unroll
        for (int q = 0; q < 8; ++q)
            os4[q] = make_float4(nr[4*q], nr[4*q+1], nr[4*q+2], nr[4*q+3]);
        out[OUT_MASK_OFF + (size_t)tok * 256 + t] = nmask;
    }

    // ---- gate softmax over the 16 slots (16-lane shuffle groups) ----
    float gb = gs + (1.f - nmask) * -1e9f;
    float gm = gb;
    #pragma unroll
    for (int off = 8; off >= 1; off >>= 1) gm = fmaxf(gm, __shfl_xor(gm, off));
    float ge = __expf(gb - gm);
    float gsum = ge;
    #pragma unroll
    for (int off = 8; off >= 1; off >>= 1) gsum += __shfl_xor(gsum, off);
    float gate = ge / gsum;

    __syncthreads();   // everyone done reading old shT
    #pragma unroll
    for (int d = 0; d < 32; ++d) shT[d * COLS + colC] = gate * nr[d];
    __syncthreads();

    // ---- mem[nh][d] = sum over slots of gate-scaled rows ----
    #pragma unroll
    for (int r = 0; r < 2; ++r) {
        int o = t + r * 256;
        int onh = o >> 5, od = o & 31;
        const float* p = &shT[od * COLS + onh * 17 + 1];
        float s = 0.f;
        #pragma unroll
        for (int sl = 0; sl < 16; ++sl) s += p[sl];
        sh_mem[onh * 33 + od] = s;
    }
    __syncthreads();

    // ---- out = mem @ Wu + bu, * res_weight + hidden; thread -> 4 consecutive elems ----
    {
        int o0  = t * 4;
        int onh = o0 >> 6;
        int hd0 = o0 & 63;
        float4 acc = *(const float4*)(bu + hd0);
        const float* memrow = &sh_mem[onh * 33];
        const float4* Wu4 = (const float4*)Wu;
        #pragma unroll
        for (int d = 0; d < 32; ++d) {
            float mv = memrow[d];
            float4 w = Wu4[d * 16 + (hd0 >> 2)];
            acc.x += mv * w.x; acc.y += mv * w.y; acc.z += mv * w.z; acc.w += mv * w.w;
        }
        float rw = resw[0];
        float4 hres = hid4[t];
        acc.x = acc.x * rw + hres.x;
        acc.y = acc.y * rw + hres.y;
        acc.z = acc.z * rw + hres.z;
        acc.w = acc.w * rw + hres.w;
        *(float4*)(out + (size_t)tok * HDIM + o0) = acc;
    }
}

extern "C" void kernel_launch(void* const* d_in, const int* in_sizes, int n_in,
                              void* d_out, int out_size, void* d_ws, size_t ws_size,
                              hipStream_t stream) {
    const float* hid  = (const float*)d_in[0];
    const float* stk  = (const float*)d_in[1];
    const float* msk  = (const float*)d_in[2];
    const float* Wa   = (const float*)d_in[3];
    const float* ba   = (const float*)d_in[4];
    const float* Wd   = (const float*)d_in[5];
    const float* bd   = (const float*)d_in[6];
    const float* Wu   = (const float*)d_in[7];
    const float* bu   = (const float*)d_in[8];
    const float* Wg   = (const float*)d_in[9];
    const float* bg   = (const float*)d_in[10];
    const float* rw   = (const float*)d_in[11];
    float* out = (float*)d_out;
    float* waT = (float*)d_ws;   // 48*1024 floats = 192 KiB scratch

    transpose_wa<<<192, 256, 0, stream>>>(Wa, waT);
    stack_fused<<<8192, 256, 0, stream>>>(hid, stk, msk, waT, ba, Wd, bd, Wu, bu, Wg, bg, rw, out);
}